// Round 13
// baseline (220.153 us; speedup 1.0000x reference)
//
#include <hip/hip_runtime.h>

typedef unsigned short u16;
typedef unsigned int u32;
typedef float f32x4 __attribute__((ext_vector_type(4)));
typedef __bf16 bf16x8 __attribute__((ext_vector_type(8)));

#define SEQ 2048
#define DM 1024

__device__ __forceinline__ float bf2f(u16 a){
  u32 b = ((u32)a) << 16; float f; __builtin_memcpy(&f, &b, 4); return f;
}
__device__ __forceinline__ u16 f2bf(float f){
  u32 b; __builtin_memcpy(&b, &f, 4);
  b += 0x7fffu + ((b >> 16) & 1u);
  return (u16)(b >> 16);
}

__device__ __forceinline__ void gload16(const void* g, void* l){
  __builtin_amdgcn_global_load_lds((const __attribute__((address_space(1))) u32*)g,
                                   (__attribute__((address_space(3))) u32*)l, 16, 0, 0);
}

#define SBAR  __builtin_amdgcn_sched_barrier(0); __builtin_amdgcn_s_barrier(); __builtin_amdgcn_sched_barrier(0);
#define VM0   asm volatile("s_waitcnt vmcnt(0)" ::: "memory"); __builtin_amdgcn_sched_barrier(0);
#define VM6   asm volatile("s_waitcnt vmcnt(6)" ::: "memory"); __builtin_amdgcn_sched_barrier(0);
#define VM8   asm volatile("s_waitcnt vmcnt(8)" ::: "memory"); __builtin_amdgcn_sched_barrier(0);

#define MFMA16(AF, BF) \
  __builtin_amdgcn_s_setprio(1); \
  _Pragma("unroll") for (int m_ = 0; m_ < 4; m_++) \
  _Pragma("unroll") for (int n_ = 0; n_ < 4; n_++) \
    acc[m_][n_] = __builtin_amdgcn_mfma_f32_16x16x32_bf16(AF[m_], BF[n_], acc[m_][n_], 0,0,0); \
  __builtin_amdgcn_s_setprio(0);

// transpose one 64x64 tile: W[K][N] f32 -> WT[N][K] bf16 (tile points to 64x65 float LDS)
__device__ __forceinline__ void trans_tile(const float* W, u16* WT, int K, int kb, int nb,
                                           float (*tile)[65], int t){
  const int N = 1024;
  #pragma unroll
  for (int i = 0; i < 4; i++){
    int idx = t + (i << 8);
    int r = idx >> 4, c = (idx & 15) << 2;
    float4 v = *(const float4*)(W + (size_t)(kb + r) * N + nb + c);
    tile[r][c] = v.x; tile[r][c+1] = v.y; tile[r][c+2] = v.z; tile[r][c+3] = v.w;
  }
  __syncthreads();
  #pragma unroll
  for (int i = 0; i < 2; i++){
    int idx = t + (i << 8);
    int n = idx >> 3, k8 = (idx & 7) << 3;
    union { u16 s[8]; int4 v; } u;
    #pragma unroll
    for (int j = 0; j < 8; j++) u.s[j] = f2bf(tile[k8 + j][n]);
    *(int4*)(WT + (size_t)(nb + n) * K + kb + k8) = u.v;
  }
}

// ---------------- ktl: QKV weight transposes (z<6) + layernorm (z==6) ----------------
struct TP { const float* src[6]; u16* dst[6]; };

__global__ __launch_bounds__(256) void ktl(TP tp, const float* __restrict__ x,
                                           const float* __restrict__ gg, const float* __restrict__ bb,
                                           u16* __restrict__ h){
  __shared__ float tile[64][65];
  int z = blockIdx.z;
  int t = threadIdx.x;
  if (z == 6){
    // layernorm role: 256 blocks grid-stride over 4096 rows
    int b0 = blockIdx.y * 16 + blockIdx.x;
    float* r1 = &tile[0][0];
    float* r2 = &tile[1][0];
    for (int row = b0; row < 4096; row += 256){
      float4 xv = ((const float4*)(x + (size_t)row * DM))[t];
      float s  = xv.x + xv.y + xv.z + xv.w;
      float s2 = xv.x*xv.x + xv.y*xv.y + xv.z*xv.z + xv.w*xv.w;
      #pragma unroll
      for (int o = 1; o < 64; o <<= 1){ s += __shfl_xor(s, o); s2 += __shfl_xor(s2, o); }
      if ((t & 63) == 0){ r1[t >> 6] = s; r2[t >> 6] = s2; }
      __syncthreads();
      float S = r1[0]+r1[1]+r1[2]+r1[3], S2 = r2[0]+r2[1]+r2[2]+r2[3];
      float mu = S * (1.0f/DM);
      float var = S2 * (1.0f/DM) - mu*mu;
      float rstd = rsqrtf(var + 1e-5f);
      float4 gv = ((const float4*)gg)[t], bv = ((const float4*)bb)[t];
      ushort4 o;
      o.x = f2bf((xv.x - mu)*rstd*gv.x + bv.x);
      o.y = f2bf((xv.y - mu)*rstd*gv.y + bv.y);
      o.z = f2bf((xv.z - mu)*rstd*gv.z + bv.z);
      o.w = f2bf((xv.w - mu)*rstd*gv.w + bv.w);
      ((ushort4*)(h + (size_t)row * DM))[t] = o;
      __syncthreads();
    }
    return;
  }
  trans_tile(tp.src[z], tp.dst[z], 1024, blockIdx.y << 6, blockIdx.x << 6, tile, t);
}

__device__ __forceinline__ float phi_elu(float v){ return v > 0.f ? v + 1.f : __expf(v); }

// ================= kqkv8: 128x256-tile, 8 waves, register-prefetch pipeline (best) =============
__global__ __launch_bounds__(512, 2) void kqkv8(
  const u16* __restrict__ h,
  const u16* wt0, const u16* wt1, const u16* wt2, const u16* wt3, const u16* wt4, const u16* wt5,
  const float* b0, const float* b1, const float* b2, const float* b3, const float* b4, const float* b5,
  u16* phiQ, u16* phiKT, u16* vT, u16* qloc, u16* kloc, u16* vlocT)
{
  extern __shared__ char smem[];
  char* LA0 = smem;
  char* LA1 = smem + 16384;
  char* LB0 = smem + 32768;
  char* LB1 = smem + 65536;

  const int t = threadIdx.x, lane = t & 63, w = t >> 6;
  const int wm = w >> 2, wn = w & 3;

  int bid = blockIdx.x;
  int swz = (bid & 7) * 96 + (bid >> 3);
  int mt = swz & 31, ntile = swz >> 5;
  int m0 = mt << 7;
  int n0g = ntile << 8;
  int wi = n0g >> 10;
  int n0 = n0g & 1023;
  const u16* Bp = wi==0?wt0: wi==1?wt1: wi==2?wt2: wi==3?wt3: wi==4?wt4: wt5;
  const float* bsel = wi==0?b0: wi==1?b1: wi==2?b2: wi==3?b3: wi==4?b4: b5;

  auto stageA = [&](char* dst, int kt){
    #pragma unroll
    for (int j = 0; j < 2; j++){
      int slot = (j << 9) + t;
      int r = slot >> 3;
      int csw = ((slot & 7) << 4) ^ ((r & 7) << 4);
      gload16((const char*)(h + (size_t)(m0 + r) * 1024 + (kt << 6)) + csw,
              dst + (((j << 9) + (w << 6)) << 4));
    }
  };
  auto stageB = [&](char* dst, int kt){
    #pragma unroll
    for (int j = 0; j < 4; j++){
      int slot = (j << 9) + t;
      int r = slot >> 3;
      int csw = ((slot & 7) << 4) ^ ((r & 7) << 4);
      gload16((const char*)(Bp + (size_t)(n0 + r) * 1024 + (kt << 6)) + csw,
              dst + (((j << 9) + (w << 6)) << 4));
    }
  };
  auto rdA = [&](const char* ab, int m, int kk) -> bf16x8 {
    int ra = (wm << 6) + (m << 4) + (lane & 15);
    return *(const bf16x8*)(ab + (ra << 7) + (((kk << 6) + ((lane >> 4) << 4)) ^ ((ra & 7) << 4)));
  };
  auto rdB = [&](const char* bb, int n, int kk) -> bf16x8 {
    int rb = (wn << 6) + (n << 4) + (lane & 15);
    return *(const bf16x8*)(bb + (rb << 7) + (((kk << 6) + ((lane >> 4) << 4)) ^ ((rb & 7) << 4)));
  };

  f32x4 acc[4][4];
  #pragma unroll
  for (int m = 0; m < 4; m++)
    #pragma unroll
    for (int n = 0; n < 4; n++) acc[m][n] = (f32x4){0.f,0.f,0.f,0.f};

  const int NT = 16;
  bf16x8 a0[4], bq0[4], a1[4], bq1[4];

  stageA(LA0, 0); stageB(LB0, 0);
  stageA(LA1, 1); stageB(LB1, 1);
  VM6 SBAR
  #pragma unroll
  for (int m = 0; m < 4; m++) a0[m] = rdA(LA0, m, 0);
  #pragma unroll
  for (int n = 0; n < 4; n++) bq0[n] = rdB(LB0, n, 0);

  #pragma unroll 1
  for (int i = 0; i < NT/2; i++){
    int e = 2*i, o = e + 1;
    int se = (e + 2 < NT) ? e + 2 : NT - 1;
    int so = (o + 2 < NT) ? o + 2 : NT - 1;
    #pragma unroll
    for (int m = 0; m < 4; m++) a1[m] = rdA(LA0, m, 1);
    #pragma unroll
    for (int n = 0; n < 4; n++) bq1[n] = rdB(LB0, n, 1);
    SBAR
    stageA(LA0, se); stageB(LB0, se);
    MFMA16(a0, bq0)
    VM6 SBAR
    #pragma unroll
    for (int m = 0; m < 4; m++) a0[m] = rdA(LA1, m, 0);
    #pragma unroll
    for (int n = 0; n < 4; n++) bq0[n] = rdB(LB1, n, 0);
    MFMA16(a1, bq1)
    #pragma unroll
    for (int m = 0; m < 4; m++) a1[m] = rdA(LA1, m, 1);
    #pragma unroll
    for (int n = 0; n < 4; n++) bq1[n] = rdB(LB1, n, 1);
    SBAR
    stageA(LA1, so); stageB(LB1, so);
    MFMA16(a0, bq0)
    VM6 SBAR
    if (i < NT/2 - 1){
      #pragma unroll
      for (int m = 0; m < 4; m++) a0[m] = rdA(LA0, m, 0);
      #pragma unroll
      for (int n = 0; n < 4; n++) bq0[n] = rdB(LB0, n, 0);
    }
    MFMA16(a1, bq1)
  }
  VM0

  #pragma unroll
  for (int n = 0; n < 4; n++){
    int col = n0 + (wn << 6) + (n << 4) + (lane & 15);
    float bv = bsel[col];
    #pragma unroll
    for (int m = 0; m < 4; m++){
      int r0 = m0 + (wm << 6) + (m << 4) + ((lane >> 4) << 2);
      float e[4];
      #pragma unroll
      for (int r = 0; r < 4; r++) e[r] = acc[m][n][r] + bv;
      if (wi == 0){
        #pragma unroll
        for (int r = 0; r < 4; r++) phiQ[(size_t)(r0 + r) * DM + col] = f2bf(phi_elu(e[r]));
      } else if (wi == 1 || wi == 2 || wi == 5){
        union { u16 s[4]; ushort4 v; } o;
        #pragma unroll
        for (int r = 0; r < 4; r++) o.s[r] = f2bf(wi == 1 ? phi_elu(e[r]) : e[r]);
        int bb = r0 >> 11, sl = r0 & 2047;
        u16* dst = (wi == 1) ? phiKT : (wi == 2 ? vT : vlocT);
        *(ushort4*)(dst + ((size_t)(bb << 10) + col) * SEQ + sl) = o.v;
      } else {
        u16* dst = wi==3 ? qloc : kloc;
        #pragma unroll
        for (int r = 0; r < 4; r++) dst[(size_t)(r0 + r) * DM + col] = f2bf(e[r]);
      }
    }
  }
}

// ================= pipe128: 128x128-tile, 4 waves, register-prefetch pipeline =================
template<int NCHUNK>
__device__ __forceinline__ void pipe128(const u16* A0c, const u16* A1c, const u16* A2c, int lda,
                                        const u16* B, int ldb, int K, int m0, int n0,
                                        char* LA0, char* LA1, char* LB0, char* LB1,
                                        f32x4 (&acc)[4][4])
{
  const int t = threadIdx.x, lane = t & 63, w = t >> 6;
  const int wm = w >> 1, wn = w & 1;
  const int NT = K >> 6;

  auto stageA = [&](char* dst, int kt){
    const u16* Ab;
    if (NCHUNK == 3){
      int ci = kt >> 4;
      const u16* cp = (ci == 0) ? A0c : ((ci == 1) ? A1c : A2c);
      Ab = cp + ((kt & 15) << 6);
    } else {
      Ab = A0c + (kt << 6);
    }
    #pragma unroll
    for (int j = 0; j < 4; j++){
      int slot = (j << 8) + t;
      int r = slot >> 3;
      int csw = ((slot & 7) << 4) ^ ((r & 7) << 4);
      gload16((const char*)(Ab + (size_t)(m0 + r) * lda) + csw,
              dst + (((j << 8) + (w << 6)) << 4));
    }
  };
  auto stageB = [&](char* dst, int kt){
    const u16* Bb = B + (kt << 6);
    #pragma unroll
    for (int j = 0; j < 4; j++){
      int slot = (j << 8) + t;
      int r = slot >> 3;
      int csw = ((slot & 7) << 4) ^ ((r & 7) << 4);
      gload16((const char*)(Bb + (size_t)(n0 + r) * ldb) + csw,
              dst + (((j << 8) + (w << 6)) << 4));
    }
  };
  auto rdA = [&](const char* ab, int m, int kk) -> bf16x8 {
    int ra = (wm << 6) + (m << 4) + (lane & 15);
    return *(const bf16x8*)(ab + (ra << 7) + (((kk << 6) + ((lane >> 4) << 4)) ^ ((ra & 7) << 4)));
  };
  auto rdB = [&](const char* bb, int n, int kk) -> bf16x8 {
    int rb = (wn << 6) + (n << 4) + (lane & 15);
    return *(const bf16x8*)(bb + (rb << 7) + (((kk << 6) + ((lane >> 4) << 4)) ^ ((rb & 7) << 4)));
  };

  bf16x8 a0[4], bq0[4], a1[4], bq1[4];

  stageA(LA0, 0); stageB(LB0, 0);
  stageA(LA1, 1); stageB(LB1, 1);
  VM8 SBAR
  #pragma unroll
  for (int m = 0; m < 4; m++) a0[m] = rdA(LA0, m, 0);
  #pragma unroll
  for (int n = 0; n < 4; n++) bq0[n] = rdB(LB0, n, 0);

  #pragma unroll 1
  for (int i = 0; i < NT/2; i++){
    int e = 2*i, o = e + 1;
    int se = (e + 2 < NT) ? e + 2 : NT - 1;
    int so = (o + 2 < NT) ? o + 2 : NT - 1;
    #pragma unroll
    for (int m = 0; m < 4; m++) a1[m] = rdA(LA0, m, 1);
    #pragma unroll
    for (int n = 0; n < 4; n++) bq1[n] = rdB(LB0, n, 1);
    SBAR
    stageA(LA0, se); stageB(LB0, se);
    MFMA16(a0, bq0)
    VM8 SBAR
    #pragma unroll
    for (int m = 0; m < 4; m++) a0[m] = rdA(LA1, m, 0);
    #pragma unroll
    for (int n = 0; n < 4; n++) bq0[n] = rdB(LB1, n, 0);
    MFMA16(a1, bq1)
    #pragma unroll
    for (int m = 0; m < 4; m++) a1[m] = rdA(LA1, m, 1);
    #pragma unroll
    for (int n = 0; n < 4; n++) bq1[n] = rdB(LB1, n, 1);
    SBAR
    stageA(LA1, so); stageB(LB1, so);
    MFMA16(a0, bq0)
    VM8 SBAR
    if (i < NT/2 - 1){
      #pragma unroll
      for (int m = 0; m < 4; m++) a0[m] = rdA(LA0, m, 0);
      #pragma unroll
      for (int n = 0; n < 4; n++) bq0[n] = rdB(LB0, n, 0);
    }
    MFMA16(a1, bq1)
  }
  VM0
}

#define PIPE_LDS \
  __shared__ char LA0[16384], LA1[16384], LB0[16384], LB1[16384];

#define EPI_COORDS \
  const int lane = threadIdx.x & 63, w = threadIdx.x >> 6; \
  const int wm = w >> 1, wn = w & 1;

#define ZERO_ACC f32x4 acc[4][4]; \
  _Pragma("unroll") for (int m = 0; m < 4; m++) _Pragma("unroll") for (int n = 0; n < 4; n++) acc[m][n] = (f32x4){0.f,0.f,0.f,0.f};

// == kkvw: {kkv K-split (256)} + {MFMA window attn (1024)} + {ksumk (2048)} + {gate wT (1280)} ==
__global__ __launch_bounds__(256) void kkvw(
  const u16* __restrict__ vT, const u16* __restrict__ phiKT,
  u16* __restrict__ kvp0, u16* __restrict__ kvp1,
  const u16* __restrict__ qloc, const u16* __restrict__ kloc,
  const u16* __restrict__ vlocT, const float* __restrict__ rel_bias,
  u16* __restrict__ wout, float* __restrict__ ks,
  const float* __restrict__ wo_s, const float* __restrict__ wg1_s, const float* __restrict__ wg2_s,
  u16* __restrict__ woT, u16* __restrict__ wg1T, u16* __restrict__ wg2T)
{
  extern __shared__ char sm[];
  const int t = threadIdx.x, lane = t & 63, w = t >> 6;
  int bid = blockIdx.x;
  if (bid < 256){
    // ---- kkv role ----
    int mt = bid & 7, nt = (bid >> 3) & 7, b = (bid >> 6) & 1, kh = bid >> 7;
    int m0 = mt << 7, n0 = nt << 7;
    const u16* A = vT + (size_t)b * DM * SEQ + (kh << 10);
    const u16* B = phiKT + (size_t)b * DM * SEQ + (kh << 10);
    char* LA0 = sm; char* LA1 = sm + 16384; char* LB0 = sm + 32768; char* LB1 = sm + 49152;
    ZERO_ACC
    pipe128<1>(A, 0, 0, SEQ, B, SEQ, 1024, m0, n0, LA0, LA1, LB0, LB1, acc);
    const int wm = w >> 1, wn = w & 1;
    u16* C = (kh ? kvp1 : kvp0) + (size_t)b * DM * DM;
    #pragma unroll
    for (int n = 0; n < 4; n++){
      int col = n0 + wn*64 + n*16 + (lane & 15);
      #pragma unroll
      for (int m = 0; m < 4; m++){
        int r0 = m0 + wm*64 + m*16 + ((lane >> 4) << 2);
        #pragma unroll
        for (int r = 0; r < 4; r++) C[(size_t)(r0 + r) * DM + col] = f2bf(acc[m][n][r]);
      }
    }
    return;
  }
  if (bid >= 3328){
    // ---- gate weight transpose role ----
    float (*tile)[65] = (float(*)[65])sm;
    int tid = bid - 3328;
    if (tid < 256){
      trans_tile(wo_s, woT, 1024, (tid >> 4) << 6, (tid & 15) << 6, tile, t);
    } else if (tid < 512){
      int q = tid - 256;
      trans_tile(wg2_s, wg2T, 1024, (q >> 4) << 6, (q & 15) << 6, tile, t);
    } else {
      int q = tid - 512;                       // 0..767: 16 nb x 48 kb
      trans_tile(wg1_s, wg1T, 3072, (q >> 4) << 6, (q & 15) << 6, tile, t);
    }
    return;
  }
  if (bid >= 1280){
    // ---- ksumk role ----
    int row = bid - 1280;
    float* red = (float*)sm;
    const ushort4* src = (const ushort4*)(phiKT + (size_t)row * SEQ);
    float s = 0.f;
    for (int i = t; i < 512; i += 256){
      ushort4 v = src[i];
      s += bf2f(v.x) + bf2f(v.y) + bf2f(v.z) + bf2f(v.w);
    }
    #pragma unroll
    for (int o = 1; o < 64; o <<= 1) s += __shfl_xor(s, o);
    if ((t & 63) == 0) red[t >> 6] = s;
    __syncthreads();
    if (t == 0) ks[row] = red[0] + red[1] + red[2] + red[3];
    return;
  }
  // ---- window-attention role ----
  char* Qs = sm;              // 8K
  char* Ks = sm + 8192;       // 16K
  char* Vs = sm + 24576;      // 16K
  char* Ps = sm + 40960;      // 16K
  float* bias_s = (float*)(sm + 57344);
  int i = bid - 256;
  int qt = i & 31, hh = (i >> 5) & 15, b = i >> 9;
  int q0 = qt << 6;
  size_t rowbase = (size_t)b * SEQ;

  #pragma unroll
  for (int j = 0; j < 2; j++){
    int c = (j << 8) + t;
    int row = c >> 3;
    int csw = ((c & 7) << 4) ^ ((row & 7) << 4);
    gload16((const char*)(qloc + (rowbase + q0 + row) * DM + hh*64) + csw,
            Qs + (((j << 8) + (w << 6)) << 4));
  }
  #pragma unroll
  for (int j = 0; j < 4; j++){
    int c = (j << 8) + t;
    int row = c >> 3;
    int csw = ((c & 7) << 4) ^ ((row & 7) << 4);
    int p = q0 + row - 32;
    p = p < 0 ? 0 : (p > SEQ-1 ? SEQ-1 : p);
    gload16((const char*)(kloc + (rowbase + p) * DM + hh*64) + csw,
            Ks + (((j << 8) + (w << 6)) << 4));
  }
  #pragma unroll
  for (int j = 0; j < 4; j++){
    int c = (j << 8) + t;
    int row = c >> 4;
    int csw = ((c & 15) << 4) ^ ((row & 7) << 4);
    int k0 = q0 - 32 + (csw >> 1);
    k0 = k0 < 0 ? 0 : (k0 > SEQ-8 ? SEQ-8 : k0);
    gload16((const char*)(vlocT + ((size_t)(b << 10) + hh*64 + row) * SEQ + k0),
            Vs + (((j << 8) + (w << 6)) << 4));
  }
  if (t < 65) bias_s[t] = rel_bias[(t + 32) * 16 + hh];
  __syncthreads();

  auto rdQ = [&](int kk) -> bf16x8 {
    int ra = (w << 4) + (lane & 15);
    return *(const bf16x8*)(Qs + (ra << 7) + (((kk << 6) + ((lane >> 4) << 4)) ^ ((ra & 7) << 4)));
  };
  auto rdK = [&](int n, int kk) -> bf16x8 {
    int rb = (n << 4) + (lane & 15);
    return *(const bf16x8*)(Ks + (rb << 7) + (((kk << 6) + ((lane >> 4) << 4)) ^ ((rb & 7) << 4)));
  };
  f32x4 sa[8];
  #pragma unroll
  for (int n = 0; n < 8; n++) sa[n] = (f32x4){0.f,0.f,0.f,0.f};
  {
    bf16x8 qf0 = rdQ(0), qf1 = rdQ(1);
    #pragma unroll
    for (int n = 0; n < 8; n++){
      sa[n] = __builtin_amdgcn_mfma_f32_16x16x32_bf16(qf0, rdK(n, 0), sa[n], 0,0,0);
      sa[n] = __builtin_amdgcn_mfma_f32_16x16x32_bf16(qf1, rdK(n, 1), sa[n], 0,0,0);
    }
  }

  int qrel = (w << 4) + ((lane >> 4) << 2);
  float m_[4] = {-1e30f, -1e30f, -1e30f, -1e30f};
  #pragma unroll
  for (int n = 0; n < 8; n++){
    int ridx = (n << 4) + (lane & 15);
    int p = q0 + ridx - 32;
    #pragma unroll
    for (int j = 0; j < 4; j++){
      int d = ridx - (qrel + j);
      bool ok = ((unsigned)d <= 64u) && ((unsigned)p < (unsigned)SEQ);
      float bb = bias_s[(unsigned)d <= 64u ? d : 0];
      float v = ok ? sa[n][j] * 0.125f + bb : -1e30f;
      sa[n][j] = v;
      m_[j] = fmaxf(m_[j], v);
    }
  }
  #pragma unroll
  for (int o = 1; o < 16; o <<= 1){
    #pragma unroll
    for (int j = 0; j < 4; j++) m_[j] = fmaxf(m_[j], __shfl_xor(m_[j], o));
  }
  float l_[4] = {0.f, 0.f, 0.f, 0.f};
  #pragma unroll
  for (int n = 0; n < 8; n++){
    #pragma unroll
    for (int j = 0; j < 4; j++){
      float e = __expf(sa[n][j] - m_[j]);
      sa[n][j] = e;
      l_[j] += e;
    }
  }
  #pragma unroll
  for (int o = 1; o < 16; o <<= 1){
    #pragma unroll
    for (int j = 0; j < 4; j++) l_[j] += __shfl_xor(l_[j], o);
  }

  #pragma unroll
  for (int n = 0; n < 8; n++){
    int colb = ((n << 4) + (lane & 15)) << 1;
    #pragma unroll
    for (int j = 0; j < 4; j++){
      int row = qrel + j;
      *(u16*)(Ps + (row << 8) + (colb ^ ((row & 7) << 4))) = f2bf(sa[n][j]);
    }
  }
  __syncthreads();

  auto rdP = [&](int kk) -> bf16x8 {
    int ra = (w << 4) + (lane & 15);
    return *(const bf16x8*)(Ps + (ra << 8) + (((kk << 6) + ((lane >> 4) << 4)) ^ ((ra & 7) << 4)));
  };
  auto rdV = [&](int n, int kk) -> bf16x8 {
    int rb = (n << 4) + (lane & 15);
    return *(const bf16x8*)(Vs + (rb << 8) + (((kk << 6) + ((lane >> 4) << 4)) ^ ((rb & 7) << 4)));
  };
  f32x4 oa[4];
  #pragma unroll
  for (int n = 0; n < 4; n++) oa[n] = (f32x4){0.f,0.f,0.f,0.f};
  #pragma unroll
  for (int kk = 0; kk < 4; kk++){
    bf16x8 pf = rdP(kk);
    #pragma unroll
    for (int n = 0; n < 4; n++)
      oa[n] = __builtin_amdgcn_mfma_f32_16x16x32_bf16(pf, rdV(n, kk), oa[n], 0,0,0);
  }

  #pragma unroll
  for (int j = 0; j < 4; j++){
    float inv = 1.0f / l_[j];
    int q = q0 + qrel + j;
    u16* dst = wout + (rowbase + q) * DM + hh*64;
    #pragma unroll
    for (int n = 0; n < 4; n++)
      dst[(n << 4) + (lane & 15)] = f2bf(oa[n][j] * inv);
  }
}

// ---------------- kdva: fused kvadd (1024 blocks) + kdenom (4096 blocks) ----------------
__global__ __launch_bounds__(256) void kdva(const u16* __restrict__ kvp0, const u16* __restrict__ kvp1,
                                            u16* __restrict__ kvT,
                                            const u16* __restrict__ phiQ, const float* __restrict__ ks,
                                            float* __restrict__ dn){
  int bid = blockIdx.x, t = threadIdx.x;
  if (bid < 1024){
    size_t i = ((size_t)bid * 256 + t) * 8;
    int4 ra = *(const int4*)(kvp0 + i);
    int4 rb = *(const int4*)(kvp1 + i);
    const u16* pa = (const u16*)&ra; const u16* pb = (const u16*)&rb;
    union { u16 s[8]; int4 v; } o;
    #pragma unroll
    for (int j = 0; j < 8; j++) o.s[j] = f2bf(bf2f(pa[j]) + bf2f(pb[j]));
    *(int4*)(kvT + i) = o.v;
    return;
  }
  int row = bid - 1024;
  ushort4 v = ((const ushort4*)(phiQ + (size_t)row * DM))[t];
  float4 kk = ((const float4*)(ks + ((size_t)(row >> 11) << 10)))[t];
  float s = bf2f(v.x)*kk.x + bf2f(v.y)*kk.y + bf2f(v.z)*kk.z + bf2f(v.w)*kk.w;
  #pragma unroll
  for (int o = 1; o < 64; o <<= 1) s += __shfl_xor(s, o);
  __shared__ float red[4];
  if ((t & 63) == 0) red[t >> 6] = s;
  __syncthreads();
  if (t == 0) dn[row] = red[0] + red[1] + red[2] + red[3];
}

// ---------------- num = phiQ . kv^T, lin = num / (denom + 1e-6) ----------------
__global__ __launch_bounds__(256) void knum(const u16* __restrict__ phiQ, const u16* __restrict__ kvT,
                                            const float* __restrict__ dn, u16* __restrict__ lin){
  PIPE_LDS
  int b = blockIdx.z;
  int m0 = blockIdx.x << 7, n0 = blockIdx.y << 7;
  const u16* A = phiQ + (size_t)b * SEQ * DM;
  const u16* B = kvT + (size_t)b * DM * DM;
  ZERO_ACC
  pipe128<1>(A, 0, 0, DM, B, DM, DM, m0, n0, LA0, LA1, LB0, LB1, acc);
  EPI_COORDS
  #pragma unroll
  for (int n = 0; n < 4; n++){
    int col = n0 + wn*64 + n*16 + (lane & 15);
    #pragma unroll
    for (int m = 0; m < 4; m++){
      int r0 = m0 + wm*64 + m*16 + ((lane >> 4) << 2);
      #pragma unroll
      for (int r = 0; r < 4; r++){
        float d = dn[(b << 11) + r0 + r] + 1e-6f;
        lin[((size_t)(b << 11) + r0 + r) * DM + col] = f2bf(acc[m][n][r] / d);
      }
    }
  }
}

// ---------------- gate GEMM 1: relu([lin,win,h] . wg1 + bg1) ----------------
__global__ __launch_bounds__(256) void kgate1(const u16* __restrict__ lin, const u16* __restrict__ win,
                                              const u16* __restrict__ h, const u16* __restrict__ wg1T,
                                              const float* __restrict__ bg1, u16* __restrict__ g1){
  PIPE_LDS
  int m0 = blockIdx.x << 7, n0 = blockIdx.y << 7;
  ZERO_ACC
  pipe128<3>(lin, win, h, DM, wg1T, 3072, 3072, m0, n0, LA0, LA1, LB0, LB1, acc);
  EPI_COORDS
  #pragma unroll
  for (int n = 0; n < 4; n++){
    int col = n0 + wn*64 + n*16 + (lane & 15);
    float bv = bg1[col];
    #pragma unroll
    for (int m = 0; m < 4; m++){
      int r0 = m0 + wm*64 + m*16 + ((lane >> 4) << 2);
      #pragma unroll
      for (int r = 0; r < 4; r++){
        float v = acc[m][n][r] + bv;
        g1[(size_t)(r0 + r) * DM + col] = f2bf(v > 0.f ? v : 0.f);
      }
    }
  }
}

// ---------------- gate GEMM 2 + sigmoid + convex combine ----------------
__global__ __launch_bounds__(256) void kgate2(const u16* __restrict__ g1, const u16* __restrict__ wg2T,
                                              const float* __restrict__ bg2, const u16* __restrict__ lin,
                                              const u16* __restrict__ win, u16* __restrict__ outc){
  PIPE_LDS
  int m0 = blockIdx.x << 7, n0 = blockIdx.y << 7;
  ZERO_ACC
  pipe128<1>(g1, 0, 0, DM, wg2T, DM, DM, m0, n0, LA0, LA1, LB0, LB1, acc);
  EPI_COORDS
  #pragma unroll
  for (int n = 0; n < 4; n++){
    int col = n0 + wn*64 + n*16 + (lane & 15);
    float bv = bg2[col];
    #pragma unroll
    for (int m = 0; m < 4; m++){
      int r0 = m0 + wm*64 + m*16 + ((lane >> 4) << 2);
      #pragma unroll
      for (int r = 0; r < 4; r++){
        size_t idx = (size_t)(r0 + r) * DM + col;
        float g = 1.0f / (1.0f + __expf(-(acc[m][n][r] + bv)));
        float lv = bf2f(lin[idx]), wv = bf2f(win[idx]);
        outc[idx] = f2bf(g * lv + (1.0f - g) * wv);
      }
    }
  }
}

// ---------------- final GEMM: outc . wo + bo + x -> fp32 out ----------------
__global__ __launch_bounds__(256) void kfinal(const u16* __restrict__ outc, const u16* __restrict__ woT,
                                              const float* __restrict__ bo, const float* __restrict__ x,
                                              float* __restrict__ out){
  PIPE_LDS
  int m0 = blockIdx.x << 7, n0 = blockIdx.y << 7;
  ZERO_ACC
  pipe128<1>(outc, 0, 0, DM, woT, DM, DM, m0, n0, LA0, LA1, LB0, LB1, acc);
  EPI_COORDS
  #pragma unroll
  for (int n = 0; n < 4; n++){
    int col = n0 + wn*64 + n*16 + (lane & 15);
    float bv = bo[col];
    #pragma unroll
    for (int m = 0; m < 4; m++){
      int r0 = m0 + wm*64 + m*16 + ((lane >> 4) << 2);
      #pragma unroll
      for (int r = 0; r < 4; r++){
        size_t idx = (size_t)(r0 + r) * DM + col;
        out[idx] = acc[m][n][r] + bv + x[idx];
      }
    }
  }
}

extern "C" void kernel_launch(void* const* d_in, const int* in_sizes, int n_in,
                              void* d_out, int out_size, void* d_ws, size_t ws_size,
                              hipStream_t stream)
{
  const float* x      = (const float*)d_in[0];
  const float* wq_lin = (const float*)d_in[1];  const float* bq_lin = (const float*)d_in[2];
  const float* wk_lin = (const float*)d_in[3];  const float* bk_lin = (const float*)d_in[4];
  const float* wv_lin = (const float*)d_in[5];  const float* bv_lin = (const float*)d_in[6];
  const float* wq_loc = (const float*)d_in[7];  const float* bq_loc = (const float*)d_in[8];
  const float* wk_loc = (const float*)d_in[9];  const float* bk_loc = (const float*)d_in[10];
  const float* wv_loc = (const float*)d_in[11]; const float* bv_loc = (const float*)d_in[12];
  const float* wo     = (const float*)d_in[13]; const float* bo     = (const float*)d_in[14];
  const float* wg1    = (const float*)d_in[15]; const float* bg1    = (const float*)d_in[16];
  const float* wg2    = (const float*)d_in[17]; const float* bg2    = (const float*)d_in[18];
  const float* rel_bias = (const float*)d_in[19];
  const float* ln_g   = (const float*)d_in[20]; const float* ln_b   = (const float*)d_in[21];

  char* ws = (char*)d_ws;
  size_t off = 0;
  auto alloc = [&](size_t bytes) -> void* {
    void* p = ws + off;
    off += (bytes + 255) & ~(size_t)255;
    return p;
  };
  const size_t MB2 = (size_t)1024 * 1024 * 2;
  const size_t ACT = (size_t)4096 * 1024 * 2;
  u16* wT[6]; for (int i = 0; i < 6; i++) wT[i] = (u16*)alloc(MB2);
  u16* woT   = (u16*)alloc(MB2);
  u16* wg1T  = (u16*)alloc((size_t)1024 * 3072 * 2);
  u16* wg2T  = (u16*)alloc(MB2);
  u16* hbf   = (u16*)alloc(ACT);
  u16* phiQ  = (u16*)alloc(ACT);
  u16* phiKT = (u16*)alloc(ACT);
  u16* vT    = (u16*)alloc(ACT);
  u16* qloc  = (u16*)alloc(ACT);
  u16* kloc  = (u16*)alloc(ACT);
  u16* vlocT = (u16*)alloc(ACT);
  u16* kvT   = (u16*)alloc(2 * MB2);
  u16* kvp0  = (u16*)alloc(2 * MB2);
  u16* kvp1  = (u16*)alloc(2 * MB2);
  float* ksum = (float*)alloc(2 * 1024 * 4);
  float* dnm  = (float*)alloc(4096 * 4);
  u16* lin   = (u16*)alloc(ACT);
  u16* win   = (u16*)alloc(ACT);
  u16* g1    = phiQ;   // reuse: phiQ dead after knum
  u16* outc  = vT;     // reuse: vT dead after kkvw

  hipFuncSetAttribute((const void*)kqkv8, hipFuncAttributeMaxDynamicSharedMemorySize, 98304);
  hipFuncSetAttribute((const void*)kkvw, hipFuncAttributeMaxDynamicSharedMemorySize, 65536);

  dim3 blk(256);
  TP tp;
  tp.src[0]=wq_lin; tp.src[1]=wk_lin; tp.src[2]=wv_lin; tp.src[3]=wq_loc; tp.src[4]=wk_loc; tp.src[5]=wv_loc;
  tp.dst[0]=wT[0]; tp.dst[1]=wT[1]; tp.dst[2]=wT[2]; tp.dst[3]=wT[3]; tp.dst[4]=wT[4]; tp.dst[5]=wT[5];

  ktl<<<dim3(16,16,7), blk, 0, stream>>>(tp, x, ln_g, ln_b, hbf);

  kqkv8<<<768, 512, 98304, stream>>>(hbf, wT[0], wT[1], wT[2], wT[3], wT[4], wT[5],
                                     bq_lin, bk_lin, bv_lin, bq_loc, bk_loc, bv_loc,
                                     phiQ, phiKT, vT, qloc, kloc, vlocT);

  kkvw<<<4608, blk, 65536, stream>>>(vT, phiKT, kvp0, kvp1, qloc, kloc, vlocT, rel_bias, win, ksum,
                                     wo, wg1, wg2, woT, wg1T, wg2T);

  kdva<<<5120, blk, 0, stream>>>(kvp0, kvp1, kvT, phiQ, ksum, dnm);

  knum<<<dim3(16,8,2), blk, 0, stream>>>(phiQ, kvT, dnm, lin);

  kgate1<<<dim3(32,8), blk, 0, stream>>>(lin, win, hbf, wg1T, bg1, g1);
  kgate2<<<dim3(32,8), blk, 0, stream>>>(g1, wg2T, bg2, lin, win, outc);
  kfinal<<<dim3(32,8), blk, 0, stream>>>(outc, woT, bo, x, (float*)d_out);
}

// Round 14
// 214.592 us; speedup vs baseline: 1.0259x; 1.0259x over previous
//
#include <hip/hip_runtime.h>

typedef unsigned short u16;
typedef unsigned int u32;
typedef float f32x4 __attribute__((ext_vector_type(4)));
typedef __bf16 bf16x8 __attribute__((ext_vector_type(8)));

#define SEQ 2048
#define DM 1024

__device__ __forceinline__ float bf2f(u16 a){
  u32 b = ((u32)a) << 16; float f; __builtin_memcpy(&f, &b, 4); return f;
}
__device__ __forceinline__ u16 f2bf(float f){
  u32 b; __builtin_memcpy(&b, &f, 4);
  b += 0x7fffu + ((b >> 16) & 1u);
  return (u16)(b >> 16);
}

__device__ __forceinline__ void gload16(const void* g, void* l){
  __builtin_amdgcn_global_load_lds((const __attribute__((address_space(1))) u32*)g,
                                   (__attribute__((address_space(3))) u32*)l, 16, 0, 0);
}

#define SBAR  __builtin_amdgcn_sched_barrier(0); __builtin_amdgcn_s_barrier(); __builtin_amdgcn_sched_barrier(0);
#define VM0   asm volatile("s_waitcnt vmcnt(0)" ::: "memory"); __builtin_amdgcn_sched_barrier(0);
#define VM6   asm volatile("s_waitcnt vmcnt(6)" ::: "memory"); __builtin_amdgcn_sched_barrier(0);
#define VM8   asm volatile("s_waitcnt vmcnt(8)" ::: "memory"); __builtin_amdgcn_sched_barrier(0);

#define MFMA16(AF, BF) \
  __builtin_amdgcn_s_setprio(1); \
  _Pragma("unroll") for (int m_ = 0; m_ < 4; m_++) \
  _Pragma("unroll") for (int n_ = 0; n_ < 4; n_++) \
    acc[m_][n_] = __builtin_amdgcn_mfma_f32_16x16x32_bf16(AF[m_], BF[n_], acc[m_][n_], 0,0,0); \
  __builtin_amdgcn_s_setprio(0);

// ---------------- ktl: fused weight convert+transpose (z<9) + layernorm (z==9) ----------------
struct TP { const float* src[9]; u16* dst[9]; int K[9]; };

__global__ __launch_bounds__(256) void ktl(TP tp, const float* __restrict__ x,
                                           const float* __restrict__ gg, const float* __restrict__ bb,
                                           u16* __restrict__ h){
  __shared__ float tile[64][65];
  int z = blockIdx.z;
  int t = threadIdx.x;
  if (z == 9){
    // layernorm role: 768 blocks grid-stride over 4096 rows
    int b0 = blockIdx.y * 16 + blockIdx.x;
    float* r1 = &tile[0][0];
    float* r2 = &tile[1][0];
    for (int row = b0; row < 4096; row += 768){
      float4 xv = ((const float4*)(x + (size_t)row * DM))[t];
      float s  = xv.x + xv.y + xv.z + xv.w;
      float s2 = xv.x*xv.x + xv.y*xv.y + xv.z*xv.z + xv.w*xv.w;
      #pragma unroll
      for (int o = 1; o < 64; o <<= 1){ s += __shfl_xor(s, o); s2 += __shfl_xor(s2, o); }
      if ((t & 63) == 0){ r1[t >> 6] = s; r2[t >> 6] = s2; }
      __syncthreads();
      float S = r1[0]+r1[1]+r1[2]+r1[3], S2 = r2[0]+r2[1]+r2[2]+r2[3];
      float mu = S * (1.0f/DM);
      float var = S2 * (1.0f/DM) - mu*mu;
      float rstd = rsqrtf(var + 1e-5f);
      float4 gv = ((const float4*)gg)[t], bv = ((const float4*)bb)[t];
      ushort4 o;
      o.x = f2bf((xv.x - mu)*rstd*gv.x + bv.x);
      o.y = f2bf((xv.y - mu)*rstd*gv.y + bv.y);
      o.z = f2bf((xv.z - mu)*rstd*gv.z + bv.z);
      o.w = f2bf((xv.w - mu)*rstd*gv.w + bv.w);
      ((ushort4*)(h + (size_t)row * DM))[t] = o;
      __syncthreads();
    }
    return;
  }
  int K = tp.K[z];
  int kb = blockIdx.y << 6, nb = blockIdx.x << 6;
  if (kb >= K) return;
  const float* W = tp.src[z];
  u16* WT = tp.dst[z];
  const int N = 1024;
  #pragma unroll
  for (int i = 0; i < 4; i++){
    int idx = t + (i << 8);
    int r = idx >> 4, c = (idx & 15) << 2;
    float4 v = *(const float4*)(W + (size_t)(kb + r) * N + nb + c);
    tile[r][c] = v.x; tile[r][c+1] = v.y; tile[r][c+2] = v.z; tile[r][c+3] = v.w;
  }
  __syncthreads();
  #pragma unroll
  for (int i = 0; i < 2; i++){
    int idx = t + (i << 8);
    int n = idx >> 3, k8 = (idx & 7) << 3;
    union { u16 s[8]; int4 v; } u;
    #pragma unroll
    for (int j = 0; j < 8; j++) u.s[j] = f2bf(tile[k8 + j][n]);
    *(int4*)(WT + (size_t)(nb + n) * K + kb + k8) = u.v;
  }
}

__device__ __forceinline__ float phi_elu(float v){ return v > 0.f ? v + 1.f : __expf(v); }

// ================= kqkv8: 128x256-tile, 8 waves, register-prefetch pipeline (best) =============
__global__ __launch_bounds__(512, 2) void kqkv8(
  const u16* __restrict__ h,
  const u16* wt0, const u16* wt1, const u16* wt2, const u16* wt3, const u16* wt4, const u16* wt5,
  const float* b0, const float* b1, const float* b2, const float* b3, const float* b4, const float* b5,
  u16* phiQ, u16* phiKT, u16* vT, u16* qloc, u16* kloc, u16* vlocT)
{
  extern __shared__ char smem[];
  char* LA0 = smem;
  char* LA1 = smem + 16384;
  char* LB0 = smem + 32768;
  char* LB1 = smem + 65536;

  const int t = threadIdx.x, lane = t & 63, w = t >> 6;
  const int wm = w >> 2, wn = w & 3;

  int bid = blockIdx.x;
  int swz = (bid & 7) * 96 + (bid >> 3);
  int mt = swz & 31, ntile = swz >> 5;
  int m0 = mt << 7;
  int n0g = ntile << 8;
  int wi = n0g >> 10;
  int n0 = n0g & 1023;
  const u16* Bp = wi==0?wt0: wi==1?wt1: wi==2?wt2: wi==3?wt3: wi==4?wt4: wt5;
  const float* bsel = wi==0?b0: wi==1?b1: wi==2?b2: wi==3?b3: wi==4?b4: b5;

  auto stageA = [&](char* dst, int kt){
    #pragma unroll
    for (int j = 0; j < 2; j++){
      int slot = (j << 9) + t;
      int r = slot >> 3;
      int csw = ((slot & 7) << 4) ^ ((r & 7) << 4);
      gload16((const char*)(h + (size_t)(m0 + r) * 1024 + (kt << 6)) + csw,
              dst + (((j << 9) + (w << 6)) << 4));
    }
  };
  auto stageB = [&](char* dst, int kt){
    #pragma unroll
    for (int j = 0; j < 4; j++){
      int slot = (j << 9) + t;
      int r = slot >> 3;
      int csw = ((slot & 7) << 4) ^ ((r & 7) << 4);
      gload16((const char*)(Bp + (size_t)(n0 + r) * 1024 + (kt << 6)) + csw,
              dst + (((j << 9) + (w << 6)) << 4));
    }
  };
  auto rdA = [&](const char* ab, int m, int kk) -> bf16x8 {
    int ra = (wm << 6) + (m << 4) + (lane & 15);
    return *(const bf16x8*)(ab + (ra << 7) + (((kk << 6) + ((lane >> 4) << 4)) ^ ((ra & 7) << 4)));
  };
  auto rdB = [&](const char* bb, int n, int kk) -> bf16x8 {
    int rb = (wn << 6) + (n << 4) + (lane & 15);
    return *(const bf16x8*)(bb + (rb << 7) + (((kk << 6) + ((lane >> 4) << 4)) ^ ((rb & 7) << 4)));
  };

  f32x4 acc[4][4];
  #pragma unroll
  for (int m = 0; m < 4; m++)
    #pragma unroll
    for (int n = 0; n < 4; n++) acc[m][n] = (f32x4){0.f,0.f,0.f,0.f};

  const int NT = 16;
  bf16x8 a0[4], bq0[4], a1[4], bq1[4];

  stageA(LA0, 0); stageB(LB0, 0);
  stageA(LA1, 1); stageB(LB1, 1);
  VM6 SBAR
  #pragma unroll
  for (int m = 0; m < 4; m++) a0[m] = rdA(LA0, m, 0);
  #pragma unroll
  for (int n = 0; n < 4; n++) bq0[n] = rdB(LB0, n, 0);

  #pragma unroll 1
  for (int i = 0; i < NT/2; i++){
    int e = 2*i, o = e + 1;
    int se = (e + 2 < NT) ? e + 2 : NT - 1;
    int so = (o + 2 < NT) ? o + 2 : NT - 1;
    #pragma unroll
    for (int m = 0; m < 4; m++) a1[m] = rdA(LA0, m, 1);
    #pragma unroll
    for (int n = 0; n < 4; n++) bq1[n] = rdB(LB0, n, 1);
    SBAR
    stageA(LA0, se); stageB(LB0, se);
    MFMA16(a0, bq0)
    VM6 SBAR
    #pragma unroll
    for (int m = 0; m < 4; m++) a0[m] = rdA(LA1, m, 0);
    #pragma unroll
    for (int n = 0; n < 4; n++) bq0[n] = rdB(LB1, n, 0);
    MFMA16(a1, bq1)
    #pragma unroll
    for (int m = 0; m < 4; m++) a1[m] = rdA(LA1, m, 1);
    #pragma unroll
    for (int n = 0; n < 4; n++) bq1[n] = rdB(LB1, n, 1);
    SBAR
    stageA(LA1, so); stageB(LB1, so);
    MFMA16(a0, bq0)
    VM6 SBAR
    if (i < NT/2 - 1){
      #pragma unroll
      for (int m = 0; m < 4; m++) a0[m] = rdA(LA0, m, 0);
      #pragma unroll
      for (int n = 0; n < 4; n++) bq0[n] = rdB(LB0, n, 0);
    }
    MFMA16(a1, bq1)
  }
  VM0

  #pragma unroll
  for (int n = 0; n < 4; n++){
    int col = n0 + (wn << 6) + (n << 4) + (lane & 15);
    float bv = bsel[col];
    #pragma unroll
    for (int m = 0; m < 4; m++){
      int r0 = m0 + (wm << 6) + (m << 4) + ((lane >> 4) << 2);
      float e[4];
      #pragma unroll
      for (int r = 0; r < 4; r++) e[r] = acc[m][n][r] + bv;
      if (wi == 0){
        #pragma unroll
        for (int r = 0; r < 4; r++) phiQ[(size_t)(r0 + r) * DM + col] = f2bf(phi_elu(e[r]));
      } else if (wi == 1 || wi == 2 || wi == 5){
        union { u16 s[4]; ushort4 v; } o;
        #pragma unroll
        for (int r = 0; r < 4; r++) o.s[r] = f2bf(wi == 1 ? phi_elu(e[r]) : e[r]);
        int bb = r0 >> 11, sl = r0 & 2047;
        u16* dst = (wi == 1) ? phiKT : (wi == 2 ? vT : vlocT);
        *(ushort4*)(dst + ((size_t)(bb << 10) + col) * SEQ + sl) = o.v;
      } else {
        u16* dst = wi==3 ? qloc : kloc;
        #pragma unroll
        for (int r = 0; r < 4; r++) dst[(size_t)(r0 + r) * DM + col] = f2bf(e[r]);
      }
    }
  }
}

// ================= pipe128: 128x128-tile, 4 waves, register-prefetch pipeline =================
template<int NCHUNK>
__device__ __forceinline__ void pipe128(const u16* A0c, const u16* A1c, const u16* A2c, int lda,
                                        const u16* B, int ldb, int K, int m0, int n0,
                                        char* LA0, char* LA1, char* LB0, char* LB1,
                                        f32x4 (&acc)[4][4])
{
  const int t = threadIdx.x, lane = t & 63, w = t >> 6;
  const int wm = w >> 1, wn = w & 1;
  const int NT = K >> 6;

  auto stageA = [&](char* dst, int kt){
    const u16* Ab;
    if (NCHUNK == 3){
      int ci = kt >> 4;
      const u16* cp = (ci == 0) ? A0c : ((ci == 1) ? A1c : A2c);
      Ab = cp + ((kt & 15) << 6);
    } else {
      Ab = A0c + (kt << 6);
    }
    #pragma unroll
    for (int j = 0; j < 4; j++){
      int slot = (j << 8) + t;
      int r = slot >> 3;
      int csw = ((slot & 7) << 4) ^ ((r & 7) << 4);
      gload16((const char*)(Ab + (size_t)(m0 + r) * lda) + csw,
              dst + (((j << 8) + (w << 6)) << 4));
    }
  };
  auto stageB = [&](char* dst, int kt){
    const u16* Bb = B + (kt << 6);
    #pragma unroll
    for (int j = 0; j < 4; j++){
      int slot = (j << 8) + t;
      int r = slot >> 3;
      int csw = ((slot & 7) << 4) ^ ((r & 7) << 4);
      gload16((const char*)(Bb + (size_t)(n0 + r) * ldb) + csw,
              dst + (((j << 8) + (w << 6)) << 4));
    }
  };
  auto rdA = [&](const char* ab, int m, int kk) -> bf16x8 {
    int ra = (wm << 6) + (m << 4) + (lane & 15);
    return *(const bf16x8*)(ab + (ra << 7) + (((kk << 6) + ((lane >> 4) << 4)) ^ ((ra & 7) << 4)));
  };
  auto rdB = [&](const char* bb, int n, int kk) -> bf16x8 {
    int rb = (wn << 6) + (n << 4) + (lane & 15);
    return *(const bf16x8*)(bb + (rb << 7) + (((kk << 6) + ((lane >> 4) << 4)) ^ ((rb & 7) << 4)));
  };

  bf16x8 a0[4], bq0[4], a1[4], bq1[4];

  stageA(LA0, 0); stageB(LB0, 0);
  stageA(LA1, 1); stageB(LB1, 1);
  VM8 SBAR
  #pragma unroll
  for (int m = 0; m < 4; m++) a0[m] = rdA(LA0, m, 0);
  #pragma unroll
  for (int n = 0; n < 4; n++) bq0[n] = rdB(LB0, n, 0);

  #pragma unroll 1
  for (int i = 0; i < NT/2; i++){
    int e = 2*i, o = e + 1;
    int se = (e + 2 < NT) ? e + 2 : NT - 1;
    int so = (o + 2 < NT) ? o + 2 : NT - 1;
    #pragma unroll
    for (int m = 0; m < 4; m++) a1[m] = rdA(LA0, m, 1);
    #pragma unroll
    for (int n = 0; n < 4; n++) bq1[n] = rdB(LB0, n, 1);
    SBAR
    stageA(LA0, se); stageB(LB0, se);
    MFMA16(a0, bq0)
    VM8 SBAR
    #pragma unroll
    for (int m = 0; m < 4; m++) a0[m] = rdA(LA1, m, 0);
    #pragma unroll
    for (int n = 0; n < 4; n++) bq0[n] = rdB(LB1, n, 0);
    MFMA16(a1, bq1)
    #pragma unroll
    for (int m = 0; m < 4; m++) a1[m] = rdA(LA1, m, 1);
    #pragma unroll
    for (int n = 0; n < 4; n++) bq1[n] = rdB(LB1, n, 1);
    SBAR
    stageA(LA1, so); stageB(LB1, so);
    MFMA16(a0, bq0)
    VM8 SBAR
    if (i < NT/2 - 1){
      #pragma unroll
      for (int m = 0; m < 4; m++) a0[m] = rdA(LA0, m, 0);
      #pragma unroll
      for (int n = 0; n < 4; n++) bq0[n] = rdB(LB0, n, 0);
    }
    MFMA16(a1, bq1)
  }
  VM0
}

#define PIPE_LDS \
  __shared__ char LA0[16384], LA1[16384], LB0[16384], LB1[16384];

#define EPI_COORDS \
  const int lane = threadIdx.x & 63, w = threadIdx.x >> 6; \
  const int wm = w >> 1, wn = w & 1;

#define ZERO_ACC f32x4 acc[4][4]; \
  _Pragma("unroll") for (int m = 0; m < 4; m++) _Pragma("unroll") for (int n = 0; n < 4; n++) acc[m][n] = (f32x4){0.f,0.f,0.f,0.f};

// ====== kkvw: fused {kkv K-split (256)} + {MFMA window attn (1024)} + {ksumk (2048)} ======
__global__ __launch_bounds__(256) void kkvw(
  const u16* __restrict__ vT, const u16* __restrict__ phiKT,
  u16* __restrict__ kvp0, u16* __restrict__ kvp1,
  const u16* __restrict__ qloc, const u16* __restrict__ kloc,
  const u16* __restrict__ vlocT, const float* __restrict__ rel_bias,
  u16* __restrict__ wout, float* __restrict__ ks)
{
  extern __shared__ char sm[];
  const int t = threadIdx.x, lane = t & 63, w = t >> 6;
  int bid = blockIdx.x;
  if (bid < 256){
    // ---- kkv role ----
    int mt = bid & 7, nt = (bid >> 3) & 7, b = (bid >> 6) & 1, kh = bid >> 7;
    int m0 = mt << 7, n0 = nt << 7;
    const u16* A = vT + (size_t)b * DM * SEQ + (kh << 10);
    const u16* B = phiKT + (size_t)b * DM * SEQ + (kh << 10);
    char* LA0 = sm; char* LA1 = sm + 16384; char* LB0 = sm + 32768; char* LB1 = sm + 49152;
    ZERO_ACC
    pipe128<1>(A, 0, 0, SEQ, B, SEQ, 1024, m0, n0, LA0, LA1, LB0, LB1, acc);
    const int wm = w >> 1, wn = w & 1;
    u16* C = (kh ? kvp1 : kvp0) + (size_t)b * DM * DM;
    #pragma unroll
    for (int n = 0; n < 4; n++){
      int col = n0 + wn*64 + n*16 + (lane & 15);
      #pragma unroll
      for (int m = 0; m < 4; m++){
        int r0 = m0 + wm*64 + m*16 + ((lane >> 4) << 2);
        #pragma unroll
        for (int r = 0; r < 4; r++) C[(size_t)(r0 + r) * DM + col] = f2bf(acc[m][n][r]);
      }
    }
    return;
  }
  if (bid >= 1280){
    // ---- ksumk role: ks[row] = sum_s phiKT[row][s], row in [0, 2048) ----
    int row = bid - 1280;
    float* red = (float*)sm;
    const ushort4* src = (const ushort4*)(phiKT + (size_t)row * SEQ);
    float s = 0.f;
    for (int i = t; i < 512; i += 256){
      ushort4 v = src[i];
      s += bf2f(v.x) + bf2f(v.y) + bf2f(v.z) + bf2f(v.w);
    }
    #pragma unroll
    for (int o = 1; o < 64; o <<= 1) s += __shfl_xor(s, o);
    if ((t & 63) == 0) red[t >> 6] = s;
    __syncthreads();
    if (t == 0) ks[row] = red[0] + red[1] + red[2] + red[3];
    return;
  }
  // ---- window-attention role ----
  char* Qs = sm;              // 8K
  char* Ks = sm + 8192;       // 16K
  char* Vs = sm + 24576;      // 16K
  char* Ps = sm + 40960;      // 16K
  float* bias_s = (float*)(sm + 57344);
  int i = bid - 256;
  int qt = i & 31, hh = (i >> 5) & 15, b = i >> 9;
  int q0 = qt << 6;
  size_t rowbase = (size_t)b * SEQ;

  #pragma unroll
  for (int j = 0; j < 2; j++){
    int c = (j << 8) + t;
    int row = c >> 3;
    int csw = ((c & 7) << 4) ^ ((row & 7) << 4);
    gload16((const char*)(qloc + (rowbase + q0 + row) * DM + hh*64) + csw,
            Qs + (((j << 8) + (w << 6)) << 4));
  }
  #pragma unroll
  for (int j = 0; j < 4; j++){
    int c = (j << 8) + t;
    int row = c >> 3;
    int csw = ((c & 7) << 4) ^ ((row & 7) << 4);
    int p = q0 + row - 32;
    p = p < 0 ? 0 : (p > SEQ-1 ? SEQ-1 : p);
    gload16((const char*)(kloc + (rowbase + p) * DM + hh*64) + csw,
            Ks + (((j << 8) + (w << 6)) << 4));
  }
  #pragma unroll
  for (int j = 0; j < 4; j++){
    int c = (j << 8) + t;
    int row = c >> 4;
    int csw = ((c & 15) << 4) ^ ((row & 7) << 4);
    int k0 = q0 - 32 + (csw >> 1);
    k0 = k0 < 0 ? 0 : (k0 > SEQ-8 ? SEQ-8 : k0);
    gload16((const char*)(vlocT + ((size_t)(b << 10) + hh*64 + row) * SEQ + k0),
            Vs + (((j << 8) + (w << 6)) << 4));
  }
  if (t < 65) bias_s[t] = rel_bias[(t + 32) * 16 + hh];
  __syncthreads();

  auto rdQ = [&](int kk) -> bf16x8 {
    int ra = (w << 4) + (lane & 15);
    return *(const bf16x8*)(Qs + (ra << 7) + (((kk << 6) + ((lane >> 4) << 4)) ^ ((ra & 7) << 4)));
  };
  auto rdK = [&](int n, int kk) -> bf16x8 {
    int rb = (n << 4) + (lane & 15);
    return *(const bf16x8*)(Ks + (rb << 7) + (((kk << 6) + ((lane >> 4) << 4)) ^ ((rb & 7) << 4)));
  };
  f32x4 sa[8];
  #pragma unroll
  for (int n = 0; n < 8; n++) sa[n] = (f32x4){0.f,0.f,0.f,0.f};
  {
    bf16x8 qf0 = rdQ(0), qf1 = rdQ(1);
    #pragma unroll
    for (int n = 0; n < 8; n++){
      sa[n] = __builtin_amdgcn_mfma_f32_16x16x32_bf16(qf0, rdK(n, 0), sa[n], 0,0,0);
      sa[n] = __builtin_amdgcn_mfma_f32_16x16x32_bf16(qf1, rdK(n, 1), sa[n], 0,0,0);
    }
  }

  int qrel = (w << 4) + ((lane >> 4) << 2);
  float m_[4] = {-1e30f, -1e30f, -1e30f, -1e30f};
  #pragma unroll
  for (int n = 0; n < 8; n++){
    int ridx = (n << 4) + (lane & 15);
    int p = q0 + ridx - 32;
    #pragma unroll
    for (int j = 0; j < 4; j++){
      int d = ridx - (qrel + j);
      bool ok = ((unsigned)d <= 64u) && ((unsigned)p < (unsigned)SEQ);
      float bb = bias_s[(unsigned)d <= 64u ? d : 0];
      float v = ok ? sa[n][j] * 0.125f + bb : -1e30f;
      sa[n][j] = v;
      m_[j] = fmaxf(m_[j], v);
    }
  }
  #pragma unroll
  for (int o = 1; o < 16; o <<= 1){
    #pragma unroll
    for (int j = 0; j < 4; j++) m_[j] = fmaxf(m_[j], __shfl_xor(m_[j], o));
  }
  float l_[4] = {0.f, 0.f, 0.f, 0.f};
  #pragma unroll
  for (int n = 0; n < 8; n++){
    #pragma unroll
    for (int j = 0; j < 4; j++){
      float e = __expf(sa[n][j] - m_[j]);
      sa[n][j] = e;
      l_[j] += e;
    }
  }
  #pragma unroll
  for (int o = 1; o < 16; o <<= 1){
    #pragma unroll
    for (int j = 0; j < 4; j++) l_[j] += __shfl_xor(l_[j], o);
  }

  #pragma unroll
  for (int n = 0; n < 8; n++){
    int colb = ((n << 4) + (lane & 15)) << 1;
    #pragma unroll
    for (int j = 0; j < 4; j++){
      int row = qrel + j;
      *(u16*)(Ps + (row << 8) + (colb ^ ((row & 7) << 4))) = f2bf(sa[n][j]);
    }
  }
  __syncthreads();

  auto rdP = [&](int kk) -> bf16x8 {
    int ra = (w << 4) + (lane & 15);
    return *(const bf16x8*)(Ps + (ra << 8) + (((kk << 6) + ((lane >> 4) << 4)) ^ ((ra & 7) << 4)));
  };
  auto rdV = [&](int n, int kk) -> bf16x8 {
    int rb = (n << 4) + (lane & 15);
    return *(const bf16x8*)(Vs + (rb << 8) + (((kk << 6) + ((lane >> 4) << 4)) ^ ((rb & 7) << 4)));
  };
  f32x4 oa[4];
  #pragma unroll
  for (int n = 0; n < 4; n++) oa[n] = (f32x4){0.f,0.f,0.f,0.f};
  #pragma unroll
  for (int kk = 0; kk < 4; kk++){
    bf16x8 pf = rdP(kk);
    #pragma unroll
    for (int n = 0; n < 4; n++)
      oa[n] = __builtin_amdgcn_mfma_f32_16x16x32_bf16(pf, rdV(n, kk), oa[n], 0,0,0);
  }

  #pragma unroll
  for (int j = 0; j < 4; j++){
    float inv = 1.0f / l_[j];
    int q = q0 + qrel + j;
    u16* dst = wout + (rowbase + q) * DM + hh*64;
    #pragma unroll
    for (int n = 0; n < 4; n++)
      dst[(n << 4) + (lane & 15)] = f2bf(oa[n][j] * inv);
  }
}

// ---------------- kdva: fused kvadd (1024 blocks) + kdenom (4096 blocks) ----------------
__global__ __launch_bounds__(256) void kdva(const u16* __restrict__ kvp0, const u16* __restrict__ kvp1,
                                            u16* __restrict__ kvT,
                                            const u16* __restrict__ phiQ, const float* __restrict__ ks,
                                            float* __restrict__ dn){
  int bid = blockIdx.x, t = threadIdx.x;
  if (bid < 1024){
    size_t i = ((size_t)bid * 256 + t) * 8;
    int4 ra = *(const int4*)(kvp0 + i);
    int4 rb = *(const int4*)(kvp1 + i);
    const u16* pa = (const u16*)&ra; const u16* pb = (const u16*)&rb;
    union { u16 s[8]; int4 v; } o;
    #pragma unroll
    for (int j = 0; j < 8; j++) o.s[j] = f2bf(bf2f(pa[j]) + bf2f(pb[j]));
    *(int4*)(kvT + i) = o.v;
    return;
  }
  int row = bid - 1024;
  ushort4 v = ((const ushort4*)(phiQ + (size_t)row * DM))[t];
  float4 kk = ((const float4*)(ks + ((size_t)(row >> 11) << 10)))[t];
  float s = bf2f(v.x)*kk.x + bf2f(v.y)*kk.y + bf2f(v.z)*kk.z + bf2f(v.w)*kk.w;
  #pragma unroll
  for (int o = 1; o < 64; o <<= 1) s += __shfl_xor(s, o);
  __shared__ float red[4];
  if ((t & 63) == 0) red[t >> 6] = s;
  __syncthreads();
  if (t == 0) dn[row] = red[0] + red[1] + red[2] + red[3];
}

// ---------------- num = phiQ . kv^T, lin = num / (denom + 1e-6) ----------------
__global__ __launch_bounds__(256) void knum(const u16* __restrict__ phiQ, const u16* __restrict__ kvT,
                                            const float* __restrict__ dn, u16* __restrict__ lin){
  PIPE_LDS
  int b = blockIdx.z;
  int m0 = blockIdx.x << 7, n0 = blockIdx.y << 7;
  const u16* A = phiQ + (size_t)b * SEQ * DM;
  const u16* B = kvT + (size_t)b * DM * DM;
  ZERO_ACC
  pipe128<1>(A, 0, 0, DM, B, DM, DM, m0, n0, LA0, LA1, LB0, LB1, acc);
  EPI_COORDS
  #pragma unroll
  for (int n = 0; n < 4; n++){
    int col = n0 + wn*64 + n*16 + (lane & 15);
    #pragma unroll
    for (int m = 0; m < 4; m++){
      int r0 = m0 + wm*64 + m*16 + ((lane >> 4) << 2);
      #pragma unroll
      for (int r = 0; r < 4; r++){
        float d = dn[(b << 11) + r0 + r] + 1e-6f;
        lin[((size_t)(b << 11) + r0 + r) * DM + col] = f2bf(acc[m][n][r] / d);
      }
    }
  }
}

// ---------------- gate GEMM 1: relu([lin,win,h] . wg1 + bg1) ----------------
__global__ __launch_bounds__(256) void kgate1(const u16* __restrict__ lin, const u16* __restrict__ win,
                                              const u16* __restrict__ h, const u16* __restrict__ wg1T,
                                              const float* __restrict__ bg1, u16* __restrict__ g1){
  PIPE_LDS
  int m0 = blockIdx.x << 7, n0 = blockIdx.y << 7;
  ZERO_ACC
  pipe128<3>(lin, win, h, DM, wg1T, 3072, 3072, m0, n0, LA0, LA1, LB0, LB1, acc);
  EPI_COORDS
  #pragma unroll
  for (int n = 0; n < 4; n++){
    int col = n0 + wn*64 + n*16 + (lane & 15);
    float bv = bg1[col];
    #pragma unroll
    for (int m = 0; m < 4; m++){
      int r0 = m0 + wm*64 + m*16 + ((lane >> 4) << 2);
      #pragma unroll
      for (int r = 0; r < 4; r++){
        float v = acc[m][n][r] + bv;
        g1[(size_t)(r0 + r) * DM + col] = f2bf(v > 0.f ? v : 0.f);
      }
    }
  }
}

// ---------------- gate GEMM 2 + sigmoid + convex combine ----------------
__global__ __launch_bounds__(256) void kgate2(const u16* __restrict__ g1, const u16* __restrict__ wg2T,
                                              const float* __restrict__ bg2, const u16* __restrict__ lin,
                                              const u16* __restrict__ win, u16* __restrict__ outc){
  PIPE_LDS
  int m0 = blockIdx.x << 7, n0 = blockIdx.y << 7;
  ZERO_ACC
  pipe128<1>(g1, 0, 0, DM, wg2T, DM, DM, m0, n0, LA0, LA1, LB0, LB1, acc);
  EPI_COORDS
  #pragma unroll
  for (int n = 0; n < 4; n++){
    int col = n0 + wn*64 + n*16 + (lane & 15);
    float bv = bg2[col];
    #pragma unroll
    for (int m = 0; m < 4; m++){
      int r0 = m0 + wm*64 + m*16 + ((lane >> 4) << 2);
      #pragma unroll
      for (int r = 0; r < 4; r++){
        size_t idx = (size_t)(r0 + r) * DM + col;
        float g = 1.0f / (1.0f + __expf(-(acc[m][n][r] + bv)));
        float lv = bf2f(lin[idx]), wv = bf2f(win[idx]);
        outc[idx] = f2bf(g * lv + (1.0f - g) * wv);
      }
    }
  }
}

// ---------------- final GEMM: outc . wo + bo + x -> fp32 out ----------------
__global__ __launch_bounds__(256) void kfinal(const u16* __restrict__ outc, const u16* __restrict__ woT,
                                              const float* __restrict__ bo, const float* __restrict__ x,
                                              float* __restrict__ out){
  PIPE_LDS
  int m0 = blockIdx.x << 7, n0 = blockIdx.y << 7;
  ZERO_ACC
  pipe128<1>(outc, 0, 0, DM, woT, DM, DM, m0, n0, LA0, LA1, LB0, LB1, acc);
  EPI_COORDS
  #pragma unroll
  for (int n = 0; n < 4; n++){
    int col = n0 + wn*64 + n*16 + (lane & 15);
    float bv = bo[col];
    #pragma unroll
    for (int m = 0; m < 4; m++){
      int r0 = m0 + wm*64 + m*16 + ((lane >> 4) << 2);
      #pragma unroll
      for (int r = 0; r < 4; r++){
        size_t idx = (size_t)(r0 + r) * DM + col;
        out[idx] = acc[m][n][r] + bv + x[idx];
      }
    }
  }
}

extern "C" void kernel_launch(void* const* d_in, const int* in_sizes, int n_in,
                              void* d_out, int out_size, void* d_ws, size_t ws_size,
                              hipStream_t stream)
{
  const float* x      = (const float*)d_in[0];
  const float* wq_lin = (const float*)d_in[1];  const float* bq_lin = (const float*)d_in[2];
  const float* wk_lin = (const float*)d_in[3];  const float* bk_lin = (const float*)d_in[4];
  const float* wv_lin = (const float*)d_in[5];  const float* bv_lin = (const float*)d_in[6];
  const float* wq_loc = (const float*)d_in[7];  const float* bq_loc = (const float*)d_in[8];
  const float* wk_loc = (const float*)d_in[9];  const float* bk_loc = (const float*)d_in[10];
  const float* wv_loc = (const float*)d_in[11]; const float* bv_loc = (const float*)d_in[12];
  const float* wo     = (const float*)d_in[13]; const float* bo     = (const float*)d_in[14];
  const float* wg1    = (const float*)d_in[15]; const float* bg1    = (const float*)d_in[16];
  const float* wg2    = (const float*)d_in[17]; const float* bg2    = (const float*)d_in[18];
  const float* rel_bias = (const float*)d_in[19];
  const float* ln_g   = (const float*)d_in[20]; const float* ln_b   = (const float*)d_in[21];

  char* ws = (char*)d_ws;
  size_t off = 0;
  auto alloc = [&](size_t bytes) -> void* {
    void* p = ws + off;
    off += (bytes + 255) & ~(size_t)255;
    return p;
  };
  const size_t MB2 = (size_t)1024 * 1024 * 2;
  const size_t ACT = (size_t)4096 * 1024 * 2;
  u16* wT[6]; for (int i = 0; i < 6; i++) wT[i] = (u16*)alloc(MB2);
  u16* woT   = (u16*)alloc(MB2);
  u16* wg1T  = (u16*)alloc((size_t)1024 * 3072 * 2);
  u16* wg2T  = (u16*)alloc(MB2);
  u16* hbf   = (u16*)alloc(ACT);
  u16* phiQ  = (u16*)alloc(ACT);
  u16* phiKT = (u16*)alloc(ACT);
  u16* vT    = (u16*)alloc(ACT);
  u16* qloc  = (u16*)alloc(ACT);
  u16* kloc  = (u16*)alloc(ACT);
  u16* vlocT = (u16*)alloc(ACT);
  u16* kvT   = (u16*)alloc(2 * MB2);
  u16* kvp0  = (u16*)alloc(2 * MB2);
  u16* kvp1  = (u16*)alloc(2 * MB2);
  float* ksum = (float*)alloc(2 * 1024 * 4);
  float* dnm  = (float*)alloc(4096 * 4);
  u16* lin   = (u16*)alloc(ACT);
  u16* win   = (u16*)alloc(ACT);
  u16* g1    = phiQ;   // reuse: phiQ dead after knum
  u16* outc  = vT;     // reuse: vT dead after kkvw

  hipFuncSetAttribute((const void*)kqkv8, hipFuncAttributeMaxDynamicSharedMemorySize, 98304);
  hipFuncSetAttribute((const void*)kkvw, hipFuncAttributeMaxDynamicSharedMemorySize, 65536);

  dim3 blk(256);
  TP tp;
  tp.src[0]=wq_lin; tp.src[1]=wk_lin; tp.src[2]=wv_lin; tp.src[3]=wq_loc; tp.src[4]=wk_loc;
  tp.src[5]=wv_loc; tp.src[6]=wo; tp.src[7]=wg1; tp.src[8]=wg2;
  tp.dst[0]=wT[0]; tp.dst[1]=wT[1]; tp.dst[2]=wT[2]; tp.dst[3]=wT[3]; tp.dst[4]=wT[4];
  tp.dst[5]=wT[5]; tp.dst[6]=woT; tp.dst[7]=wg1T; tp.dst[8]=wg2T;
  for (int i = 0; i < 9; i++) tp.K[i] = (i == 7) ? 3072 : 1024;

  ktl<<<dim3(16,48,10), blk, 0, stream>>>(tp, x, ln_g, ln_b, hbf);

  kqkv8<<<768, 512, 98304, stream>>>(hbf, wT[0], wT[1], wT[2], wT[3], wT[4], wT[5],
                                     bq_lin, bk_lin, bv_lin, bq_loc, bk_loc, bv_loc,
                                     phiQ, phiKT, vT, qloc, kloc, vlocT);

  kkvw<<<3328, blk, 65536, stream>>>(vT, phiKT, kvp0, kvp1, qloc, kloc, vlocT, rel_bias, win, ksum);

  kdva<<<5120, blk, 0, stream>>>(kvp0, kvp1, kvT, phiQ, ksum, dnm);

  knum<<<dim3(16,8,2), blk, 0, stream>>>(phiQ, kvT, dnm, lin);

  kgate1<<<dim3(32,8), blk, 0, stream>>>(lin, win, hbf, wg1T, bg1, g1);
  kgate2<<<dim3(32,8), blk, 0, stream>>>(g1, wg2T, bg2, lin, win, outc);
  kfinal<<<dim3(32,8), blk, 0, stream>>>(outc, woT, bo, x, (float*)d_out);
}